// Round 21
// baseline (48.089 us; speedup 1.0000x reference)
//
#include <hip/hip_runtime.h>
#include <hip/hip_fp8.h>
#include <stdint.h>

#define NPAIR 4096
#define N2    8192      // 2N rows
#define DIM   256
#define NTILE 8256      // 128*129/2 upper-triangle 64x64 tiles
#define NREP  2         // DIAGNOSTIC: each tile computed by NREP blocks
// inputs pre-scaled by sqrt(log2(e)/T): acc == log2(e)/T * sim
#define SCALE_IN 1.6986436f
#define SCALE1 0x7F7F7F7F   // E8M0 1.0 in every byte (opsel-proof)
#define LN_REP 0.6931471805599453f   // ln(NREP), subtracted per row in finalize

typedef int   i32x4  __attribute__((ext_vector_type(4)));
typedef int   i32x8  __attribute__((ext_vector_type(8)));
typedef float f32x16 __attribute__((ext_vector_type(16)));

static __device__ __forceinline__ uint8_t f2fp8(float f) {
    __hip_fp8_e4m3 v(f);                 // OCP e4m3fn, RNE saturating
    return *reinterpret_cast<uint8_t*>(&v);
}

// reps FRAGMENT-TILED for mfma_scale 32x32x64, coalesced sub-blocks (r20).

// ---------------- Kernel A: normalize rows + positive dot + zero rowsum ----
__global__ __launch_bounds__(256) void normalize_kernel(
    const float* __restrict__ emb_i, const float* __restrict__ emb_j,
    uint8_t* __restrict__ reps, float* __restrict__ pdot,
    float* __restrict__ rowsum) {
    int i = blockIdx.x * 4 + (threadIdx.x >> 6);
    int l = threadIdx.x & 63;       // 4 floats each: dims 4l..4l+3
    float4 a = ((const float4*)(emb_i + (size_t)i * DIM))[l];
    float4 b = ((const float4*)(emb_j + (size_t)i * DIM))[l];
    float si = a.x*a.x + a.y*a.y + a.z*a.z + a.w*a.w;
    float sj = b.x*b.x + b.y*b.y + b.z*b.z + b.w*b.w;
    float dp = a.x*b.x + a.y*b.y + a.z*b.z + a.w*b.w;
    #pragma unroll
    for (int off = 32; off; off >>= 1) {
        si += __shfl_xor(si, off);
        sj += __shfl_xor(sj, off);
        dp += __shfl_xor(dp, off);
    }
    float ri = 1.0f / fmaxf(sqrtf(si), 1e-12f);
    float rj = 1.0f / fmaxf(sqrtf(sj), 1e-12f);
    float riS = ri * SCALE_IN, rjS = rj * SCALE_IN;

    uchar4 ua, ub;
    ua.x = f2fp8(a.x * riS); ua.y = f2fp8(a.y * riS);
    ua.z = f2fp8(a.z * riS); ua.w = f2fp8(a.w * riS);
    ub.x = f2fp8(b.x * rjS); ub.y = f2fp8(b.y * rjS);
    ub.z = f2fp8(b.z * rjS); ub.w = f2fp8(b.w * rjS);

    // tiled store for d0 = 4l: ktile = l>>4, piece = (l>>2)&1,
    // khalf = (l>>3)&1, off = 4*(l&3)
    int ii = i + NPAIR;
    int pc  = (l >> 2) & 1;
    int kh  = (l >> 3) & 1;
    int off4 = 4 * (l & 3);
    int idxA = (((i  >> 5) * 4 + (l >> 4)) * 2048) + pc * 1024
             + (kh * 32 + (i  & 31)) * 16 + off4;
    int idxB = (((ii >> 5) * 4 + (l >> 4)) * 2048) + pc * 1024
             + (kh * 32 + (ii & 31)) * 16 + off4;
    *(uchar4*)(reps + idxA) = ua;
    *(uchar4*)(reps + idxB) = ub;

    if (l == 0) pdot[i] = dp * ri * rj;       // positives fp32, unscaled
    if (l < 2)  rowsum[2 * i + l] = 0.f;
}

// ---------- Kernel B: DIAGNOSTIC 2x-replicated per-wave 64x64 tiles -------
// Body byte-identical to r20 (best, 34.1us). Grid is NREP x NTILE: waves
// idx and idx+NTILE compute the SAME tile from different blocks (defeats
// CSE; genuine 2x work) so simexp's dur_us (~45us) exceeds the harness
// poison fills (~40us) and FINALLY surfaces full rocprof counters
// (MfmaUtil/VALUBusy/Occupancy/VGPR) for the hot kernel. rowsum = 2*D;
// finalize subtracts ln2 per row. Next round reverts NREP.
__global__ __launch_bounds__(256, 4) void simexp_kernel(
    const uint8_t* __restrict__ reps, float* __restrict__ rowsum) {
    int t = threadIdx.x;
    int l = t & 63;

    int idx = blockIdx.x * 4 + (t >> 6);
    if (idx >= NTILE) idx -= NTILE;     // replica block: same tile
    // anti-diagonal decode over n=128 tile grid: C(d) = d*(257-d)/2
    int d = (int)((257.0f - sqrtf(257.0f * 257.0f - 8.0f * (float)idx)) * 0.5f);
    while (d * (257 - d) / 2 > idx) --d;
    while ((d + 1) * (256 - d) / 2 <= idx) ++d;
    int i0 = idx - d * (257 - d) / 2;
    int brow = i0 * 64;
    int bcol = (i0 + d) * 64;
    int R0A = i0 * 2;               // 32-row fragment blocks (+mi)
    int R0B = (i0 + d) * 2;         // +ni

    f32x16 acc[2][2];
    #pragma unroll
    for (int mi = 0; mi < 2; ++mi)
        #pragma unroll
        for (int ni = 0; ni < 2; ++ni)
            acc[mi][ni] = (f32x16)(0.f);

    for (int ks = 0; ks < 4; ++ks) {    // 4 K-steps of 64
        i32x8 a[2], b[2];
        #pragma unroll
        for (int q = 0; q < 2; ++q) {
            const uint8_t* ta = reps + (size_t)(((R0A + q) * 4 + ks) * 2048);
            const uint8_t* tb = reps + (size_t)(((R0B + q) * 4 + ks) * 2048);
            i32x4 a0 = ((const i32x4*)ta)[l];
            i32x4 a1 = ((const i32x4*)(ta + 1024))[l];
            i32x4 b0 = ((const i32x4*)tb)[l];
            i32x4 b1 = ((const i32x4*)(tb + 1024))[l];
            a[q] = (i32x8){a0.x, a0.y, a0.z, a0.w, a1.x, a1.y, a1.z, a1.w};
            b[q] = (i32x8){b0.x, b0.y, b0.z, b0.w, b1.x, b1.y, b1.z, b1.w};
        }
        __builtin_amdgcn_s_setprio(1);
        #pragma unroll
        for (int mi = 0; mi < 2; ++mi)
            #pragma unroll
            for (int ni = 0; ni < 2; ++ni)
                acc[mi][ni] = __builtin_amdgcn_mfma_scale_f32_32x32x64_f8f6f4(
                    a[mi], b[ni], acc[mi][ni],
                    0, 0,               // cbsz=fp8, blgp=fp8
                    0, SCALE1,          // opsel_a, scale_a = 1.0
                    0, SCALE1);         // opsel_b, scale_b = 1.0
        __builtin_amdgcn_s_setprio(0);
    }

    // Epilogue. 32x32 C/D: col = lane&31, row = (v&3)+8*(v>>2)+4*(lane>>5)
    int c32 = l & 31;
    int h   = l >> 5;
    float csum[2] = {0.f, 0.f};

    if (d != 0) {                   // off-diagonal: unmasked, rows + cols
        float rpar[32];             // u = mi*16 + (v&3)+4*(v>>2)
        #pragma unroll
        for (int mi = 0; mi < 2; ++mi) {
            #pragma unroll
            for (int v = 0; v < 16; ++v) {
                float e0 = exp2f(acc[mi][0][v]);
                float e1 = exp2f(acc[mi][1][v]);
                csum[0] += e0;
                csum[1] += e1;
                rpar[mi * 16 + (v & 3) + 4 * (v >> 2)] = e0 + e1;
            }
        }
        // butterfly multi-reduce (31 shuffles): lane c32 ends with row sum u=c32
        bool s0 = (c32 & 1);
        float w16[16];
        #pragma unroll
        for (int i = 0; i < 16; ++i) {
            float keep = s0 ? rpar[2 * i + 1] : rpar[2 * i];
            float send = s0 ? rpar[2 * i]     : rpar[2 * i + 1];
            w16[i] = keep + __shfl_xor(send, 1);
        }
        bool s1 = (c32 & 2);
        float w8[8];
        #pragma unroll
        for (int i = 0; i < 8; ++i) {
            float keep = s1 ? w16[2 * i + 1] : w16[2 * i];
            float send = s1 ? w16[2 * i]     : w16[2 * i + 1];
            w8[i] = keep + __shfl_xor(send, 2);
        }
        bool s2 = (c32 & 4);
        float w4[4];
        #pragma unroll
        for (int i = 0; i < 4; ++i) {
            float keep = s2 ? w8[2 * i + 1] : w8[2 * i];
            float send = s2 ? w8[2 * i]     : w8[2 * i + 1];
            w4[i] = keep + __shfl_xor(send, 4);
        }
        bool s3 = (c32 & 8);
        float w2[2];
        #pragma unroll
        for (int i = 0; i < 2; ++i) {
            float keep = s3 ? w4[2 * i + 1] : w4[2 * i];
            float send = s3 ? w4[2 * i]     : w4[2 * i + 1];
            w2[i] = keep + __shfl_xor(send, 8);
        }
        bool s4 = (c32 & 16);
        float keep = s4 ? w2[1] : w2[0];
        float send = s4 ? w2[0] : w2[1];
        float rv = keep + __shfl_xor(send, 16);

        csum[0] += __shfl_xor(csum[0], 32);
        csum[1] += __shfl_xor(csum[1], 32);
        float cv = h ? csum[1] : csum[0];
        atomicAdd(&rowsum[bcol + h * 32 + c32], cv);     // 64 disjoint cols
        int grow = brow + (c32 >> 4) * 32 + (c32 & 3)
                 + 8 * ((c32 & 15) >> 2) + 4 * h;
        atomicAdd(&rowsum[grow], rv);                    // 64 disjoint rows
    } else {                        // diagonal tile: masked, cols only
        #pragma unroll
        for (int mi = 0; mi < 2; ++mi) {
            #pragma unroll
            for (int v = 0; v < 16; ++v) {
                int grow = brow + mi * 32 + (v & 3) + 8 * (v >> 2) + 4 * h;
                #pragma unroll
                for (int ni = 0; ni < 2; ++ni) {
                    float e = exp2f(acc[mi][ni][v]);
                    int gcol = bcol + ni * 32 + c32;
                    e = (grow == gcol) ? 0.f : e;        // main diagonal
                    csum[ni] += e;
                }
            }
        }
        csum[0] += __shfl_xor(csum[0], 32);
        csum[1] += __shfl_xor(csum[1], 32);
        float cv = h ? csum[1] : csum[0];
        atomicAdd(&rowsum[bcol + h * 32 + c32], cv);
    }
}

// ---------------- Kernel C: finalize (rowsum holds NREP*D) ----------------
__global__ __launch_bounds__(256) void finalize_kernel(
    const float* __restrict__ rowsum, const float* __restrict__ pdot,
    float* __restrict__ out) {
    int t = threadIdx.x;
    __shared__ float reds[4], redp[4];
    const float4* rs4 = (const float4*)rowsum;
    const float4* pd4 = (const float4*)pdot;
    float s = 0.f, p = 0.f;
    for (int r = t; r < N2 / 4; r += 256) {
        float4 v = rs4[r];
        s += __logf(v.x) + __logf(v.y) + __logf(v.z) + __logf(v.w);
    }
    for (int r = t; r < NPAIR / 4; r += 256) {
        float4 v = pd4[r];
        p += v.x + v.y + v.z + v.w;
    }
    #pragma unroll
    for (int off = 32; off; off >>= 1) {
        s += __shfl_xor(s, off);
        p += __shfl_xor(p, off);
    }
    if ((t & 63) == 0) { reds[t >> 6] = s; redp[t >> 6] = p; }
    __syncthreads();
    if (t == 0) {
        float S = reds[0] + reds[1] + reds[2] + reds[3];
        float P = redp[0] + redp[1] + redp[2] + redp[3];
        // log(NREP*D) = ln(NREP) + log(D)  -> subtract LN_REP per row
        out[0] = (S - 4.0f * P) / (float)N2 - LN_REP;
    }
}

extern "C" void kernel_launch(void* const* d_in, const int* in_sizes, int n_in,
                              void* d_out, int out_size, void* d_ws, size_t ws_size,
                              hipStream_t stream) {
    const float* emb_i = (const float*)d_in[0];
    const float* emb_j = (const float*)d_in[1];
    float* out = (float*)d_out;

    char* ws = (char*)d_ws;
    float*    rowsum = (float*)ws;                    // 8192 * 4 B
    float*    pdot   = (float*)(ws + 32768);          // 4096 * 4 B
    uint8_t*  reps   = (uint8_t*)(ws + 65536);        // 8192*256 B (fp8 tiled)

    normalize_kernel<<<NPAIR / 4, 256, 0, stream>>>(emb_i, emb_j, reps,
                                                    pdot, rowsum);
    simexp_kernel<<<NREP * NTILE / 4, 256, 0, stream>>>(reps, rowsum);
    finalize_kernel<<<1, 256, 0, stream>>>(rowsum, pdot, out);
}

// Round 22
// 32.610 us; speedup vs baseline: 1.4747x; 1.4747x over previous
//
#include <hip/hip_runtime.h>
#include <hip/hip_fp8.h>
#include <stdint.h>

#define NPAIR 4096
#define N2    8192      // 2N rows
#define DIM   256
#define NTILE 8256      // 128*129/2 upper-triangle 64x64 tiles
#define FINBLK 16       // finalize blocks
// inputs pre-scaled by sqrt(log2(e)/T): acc == log2(e)/T * sim
#define SCALE_IN 1.6986436f
#define SCALE1 0x7F7F7F7F   // E8M0 1.0 in every byte (opsel-proof)

typedef int   i32x4  __attribute__((ext_vector_type(4)));
typedef int   i32x8  __attribute__((ext_vector_type(8)));
typedef float f32x16 __attribute__((ext_vector_type(16)));

static __device__ __forceinline__ uint8_t f2fp8(float f) {
    __hip_fp8_e4m3 v(f);                 // OCP e4m3fn, RNE saturating
    return *reinterpret_cast<uint8_t*>(&v);
}

// pack 4 floats -> 4 OCP e4m3 bytes (byte k = input k)
static __device__ __forceinline__ uint32_t pk4_fp8(float x, float y,
                                                   float z, float w) {
#if __has_builtin(__builtin_amdgcn_cvt_pk_fp8_f32)
    int v = 0;
    v = __builtin_amdgcn_cvt_pk_fp8_f32(x, y, v, false);  // bytes 0,1
    v = __builtin_amdgcn_cvt_pk_fp8_f32(z, w, v, true);   // bytes 2,3
    return (uint32_t)v;
#else
    return (uint32_t)f2fp8(x) | ((uint32_t)f2fp8(y) << 8)
         | ((uint32_t)f2fp8(z) << 16) | ((uint32_t)f2fp8(w) << 24);
#endif
}

// reps FRAGMENT-TILED for mfma_scale 32x32x64, coalesced sub-blocks (r20):
// byte index of (row i, dim d) = ((i>>5)*4 + (d>>6))*2048 + ((d>>4)&1)*1024
//                              + (((d>>5)&1)*32 + (i&31))*16 + (d&15)

// ---------------- Kernel A: normalize + pdot + zero rowsum/partials -------
__global__ __launch_bounds__(256) void normalize_kernel(
    const float* __restrict__ emb_i, const float* __restrict__ emb_j,
    uint8_t* __restrict__ reps, float* __restrict__ pdot,
    float* __restrict__ rowsum, float* __restrict__ partials,
    unsigned int* __restrict__ counter) {
    int i = blockIdx.x * 4 + (threadIdx.x >> 6);
    int l = threadIdx.x & 63;       // 4 floats each: dims 4l..4l+3
    float4 a = ((const float4*)(emb_i + (size_t)i * DIM))[l];
    float4 b = ((const float4*)(emb_j + (size_t)i * DIM))[l];
    float si = a.x*a.x + a.y*a.y + a.z*a.z + a.w*a.w;
    float sj = b.x*b.x + b.y*b.y + b.z*b.z + b.w*b.w;
    float dp = a.x*b.x + a.y*b.y + a.z*b.z + a.w*b.w;
    #pragma unroll
    for (int off = 32; off; off >>= 1) {
        si += __shfl_xor(si, off);
        sj += __shfl_xor(sj, off);
        dp += __shfl_xor(dp, off);
    }
    float ri = 1.0f / fmaxf(sqrtf(si), 1e-12f);
    float rj = 1.0f / fmaxf(sqrtf(sj), 1e-12f);
    float riS = ri * SCALE_IN, rjS = rj * SCALE_IN;

    uint32_t ua = pk4_fp8(a.x * riS, a.y * riS, a.z * riS, a.w * riS);
    uint32_t ub = pk4_fp8(b.x * rjS, b.y * rjS, b.z * rjS, b.w * rjS);

    // tiled store for d0 = 4l: ktile = l>>4, piece = (l>>2)&1,
    // khalf = (l>>3)&1, off = 4*(l&3)
    int ii = i + NPAIR;
    int pc  = (l >> 2) & 1;
    int kh  = (l >> 3) & 1;
    int off4 = 4 * (l & 3);
    int idxA = (((i  >> 5) * 4 + (l >> 4)) * 2048) + pc * 1024
             + (kh * 32 + (i  & 31)) * 16 + off4;
    int idxB = (((ii >> 5) * 4 + (l >> 4)) * 2048) + pc * 1024
             + (kh * 32 + (ii & 31)) * 16 + off4;
    *(uint32_t*)(reps + idxA) = ua;
    *(uint32_t*)(reps + idxB) = ub;

    if (l == 0) pdot[i] = dp * ri * rj;       // positives fp32, unscaled
    if (l < 2)  rowsum[2 * i + l] = 0.f;
    if (i == 0 && l == 0) {
        partials[0] = 0.f; partials[1] = 0.f; *counter = 0u;
    }
}

// ---------- Kernel B: BARRIER-FREE per-wave 64x64 tiles, MX-scaled fp8 ----
// Byte-identical to r20's best (34.1us): 2 coalesced int4 loads/fragment,
// mfma_scale_f32_32x32x64_f8f6f4 (scales=1.0), 32x32 C/D epilogue with
// butterfly multi-reduce, 2 disjoint atomics/lane.
__global__ __launch_bounds__(256, 4) void simexp_kernel(
    const uint8_t* __restrict__ reps, float* __restrict__ rowsum) {
    int t = threadIdx.x;
    int l = t & 63;

    // anti-diagonal decode over n=128 tile grid: C(d) = d*(257-d)/2
    int idx = blockIdx.x * 4 + (t >> 6);
    int d = (int)((257.0f - sqrtf(257.0f * 257.0f - 8.0f * (float)idx)) * 0.5f);
    while (d * (257 - d) / 2 > idx) --d;
    while ((d + 1) * (256 - d) / 2 <= idx) ++d;
    int i0 = idx - d * (257 - d) / 2;
    int brow = i0 * 64;
    int bcol = (i0 + d) * 64;
    int R0A = i0 * 2;               // 32-row fragment blocks (+mi)
    int R0B = (i0 + d) * 2;         // +ni

    f32x16 acc[2][2];
    #pragma unroll
    for (int mi = 0; mi < 2; ++mi)
        #pragma unroll
        for (int ni = 0; ni < 2; ++ni)
            acc[mi][ni] = (f32x16)(0.f);

    for (int ks = 0; ks < 4; ++ks) {    // 4 K-steps of 64
        i32x8 a[2], b[2];
        #pragma unroll
        for (int q = 0; q < 2; ++q) {
            const uint8_t* ta = reps + (size_t)(((R0A + q) * 4 + ks) * 2048);
            const uint8_t* tb = reps + (size_t)(((R0B + q) * 4 + ks) * 2048);
            i32x4 a0 = ((const i32x4*)ta)[l];
            i32x4 a1 = ((const i32x4*)(ta + 1024))[l];
            i32x4 b0 = ((const i32x4*)tb)[l];
            i32x4 b1 = ((const i32x4*)(tb + 1024))[l];
            a[q] = (i32x8){a0.x, a0.y, a0.z, a0.w, a1.x, a1.y, a1.z, a1.w};
            b[q] = (i32x8){b0.x, b0.y, b0.z, b0.w, b1.x, b1.y, b1.z, b1.w};
        }
        __builtin_amdgcn_s_setprio(1);
        #pragma unroll
        for (int mi = 0; mi < 2; ++mi)
            #pragma unroll
            for (int ni = 0; ni < 2; ++ni)
                acc[mi][ni] = __builtin_amdgcn_mfma_scale_f32_32x32x64_f8f6f4(
                    a[mi], b[ni], acc[mi][ni],
                    0, 0,               // cbsz=fp8, blgp=fp8
                    0, SCALE1,          // opsel_a, scale_a = 1.0
                    0, SCALE1);         // opsel_b, scale_b = 1.0
        __builtin_amdgcn_s_setprio(0);
    }

    // Epilogue. 32x32 C/D: col = lane&31, row = (v&3)+8*(v>>2)+4*(lane>>5)
    int c32 = l & 31;
    int h   = l >> 5;
    float csum[2] = {0.f, 0.f};

    if (d != 0) {                   // off-diagonal: unmasked, rows + cols
        float rpar[32];             // u = mi*16 + (v&3)+4*(v>>2)
        #pragma unroll
        for (int mi = 0; mi < 2; ++mi) {
            #pragma unroll
            for (int v = 0; v < 16; ++v) {
                float e0 = exp2f(acc[mi][0][v]);
                float e1 = exp2f(acc[mi][1][v]);
                csum[0] += e0;
                csum[1] += e1;
                rpar[mi * 16 + (v & 3) + 4 * (v >> 2)] = e0 + e1;
            }
        }
        // butterfly multi-reduce (31 shuffles): lane c32 ends with row sum u=c32
        bool s0 = (c32 & 1);
        float w16[16];
        #pragma unroll
        for (int i = 0; i < 16; ++i) {
            float keep = s0 ? rpar[2 * i + 1] : rpar[2 * i];
            float send = s0 ? rpar[2 * i]     : rpar[2 * i + 1];
            w16[i] = keep + __shfl_xor(send, 1);
        }
        bool s1 = (c32 & 2);
        float w8[8];
        #pragma unroll
        for (int i = 0; i < 8; ++i) {
            float keep = s1 ? w16[2 * i + 1] : w16[2 * i];
            float send = s1 ? w16[2 * i]     : w16[2 * i + 1];
            w8[i] = keep + __shfl_xor(send, 2);
        }
        bool s2 = (c32 & 4);
        float w4[4];
        #pragma unroll
        for (int i = 0; i < 4; ++i) {
            float keep = s2 ? w8[2 * i + 1] : w8[2 * i];
            float send = s2 ? w8[2 * i]     : w8[2 * i + 1];
            w4[i] = keep + __shfl_xor(send, 4);
        }
        bool s3 = (c32 & 8);
        float w2[2];
        #pragma unroll
        for (int i = 0; i < 2; ++i) {
            float keep = s3 ? w4[2 * i + 1] : w4[2 * i];
            float send = s3 ? w4[2 * i]     : w4[2 * i + 1];
            w2[i] = keep + __shfl_xor(send, 8);
        }
        bool s4 = (c32 & 16);
        float keep = s4 ? w2[1] : w2[0];
        float send = s4 ? w2[0] : w2[1];
        float rv = keep + __shfl_xor(send, 16);

        csum[0] += __shfl_xor(csum[0], 32);
        csum[1] += __shfl_xor(csum[1], 32);
        float cv = h ? csum[1] : csum[0];
        atomicAdd(&rowsum[bcol + h * 32 + c32], cv);     // 64 disjoint cols
        int grow = brow + (c32 >> 4) * 32 + (c32 & 3)
                 + 8 * ((c32 & 15) >> 2) + 4 * h;
        atomicAdd(&rowsum[grow], rv);                    // 64 disjoint rows
    } else {                        // diagonal tile: masked, cols only
        #pragma unroll
        for (int mi = 0; mi < 2; ++mi) {
            #pragma unroll
            for (int v = 0; v < 16; ++v) {
                int grow = brow + mi * 32 + (v & 3) + 8 * (v >> 2) + 4 * h;
                #pragma unroll
                for (int ni = 0; ni < 2; ++ni) {
                    float e = exp2f(acc[mi][ni][v]);
                    int gcol = bcol + ni * 32 + c32;
                    e = (grow == gcol) ? 0.f : e;        // main diagonal
                    csum[ni] += e;
                }
            }
        }
        csum[0] += __shfl_xor(csum[0], 32);
        csum[1] += __shfl_xor(csum[1], 32);
        float cv = h ? csum[1] : csum[0];
        atomicAdd(&rowsum[bcol + h * 32 + c32], cv);
    }
}

// ---------------- Kernel C: PARALLEL finalize (16 blocks) -----------------
// Each block reduces a slice of log(rowsum) and pdot, atomicAdds the two
// scalars into partials[0..1]; the last-arriving block (16-block counter,
// fences) writes out. 16 fences/atomics are negligible (r3's cost was 2080).
__global__ __launch_bounds__(256) void finalize_kernel(
    const float* __restrict__ rowsum, const float* __restrict__ pdot,
    float* __restrict__ partials, unsigned int* __restrict__ counter,
    float* __restrict__ out) {
    int t = threadIdx.x;
    int g = blockIdx.x * 256 + t;       // 0..4095
    __shared__ float reds[4], redp[4];
    __shared__ int lastFlag;
    const float4* rs4 = (const float4*)rowsum;
    const float4* pd4 = (const float4*)pdot;
    float s = 0.f, p = 0.f;
    if (g < N2 / 4) {
        float4 v = rs4[g];
        s = __logf(v.x) + __logf(v.y) + __logf(v.z) + __logf(v.w);
    }
    if (g < NPAIR / 4) {
        float4 v = pd4[g];
        p = v.x + v.y + v.z + v.w;
    }
    #pragma unroll
    for (int off = 32; off; off >>= 1) {
        s += __shfl_xor(s, off);
        p += __shfl_xor(p, off);
    }
    if ((t & 63) == 0) { reds[t >> 6] = s; redp[t >> 6] = p; }
    __syncthreads();
    if (t == 0) {
        float S = reds[0] + reds[1] + reds[2] + reds[3];
        float P = redp[0] + redp[1] + redp[2] + redp[3];
        atomicAdd(&partials[0], S);
        atomicAdd(&partials[1], P);
        __threadfence();
        unsigned prev = atomicAdd(counter, 1u);
        lastFlag = (prev == FINBLK - 1);
        __threadfence();
    }
    __syncthreads();
    if (lastFlag && t == 0) {
        float S = __hip_atomic_load(&partials[0], __ATOMIC_ACQUIRE,
                                    __HIP_MEMORY_SCOPE_AGENT);
        float P = __hip_atomic_load(&partials[1], __ATOMIC_ACQUIRE,
                                    __HIP_MEMORY_SCOPE_AGENT);
        // loss = (sum log D - (2/T)*2*sum(dp)) / 2N ; (2/T)*2 folded: 4*P
        out[0] = (S - 4.0f * P) / (float)N2;
    }
}

extern "C" void kernel_launch(void* const* d_in, const int* in_sizes, int n_in,
                              void* d_out, int out_size, void* d_ws, size_t ws_size,
                              hipStream_t stream) {
    const float* emb_i = (const float*)d_in[0];
    const float* emb_j = (const float*)d_in[1];
    float* out = (float*)d_out;

    char* ws = (char*)d_ws;
    float*        rowsum   = (float*)ws;                    // 8192 * 4 B
    float*        pdot     = (float*)(ws + 32768);          // 4096 * 4 B
    float*        partials = (float*)(ws + 49152);          // 2 * 4 B
    unsigned int* counter  = (unsigned int*)(ws + 49216);   // 4 B
    uint8_t*      reps     = (uint8_t*)(ws + 65536);        // 2 MB fp8 tiled

    normalize_kernel<<<NPAIR / 4, 256, 0, stream>>>(emb_i, emb_j, reps, pdot,
                                                    rowsum, partials, counter);
    simexp_kernel<<<NTILE / 4, 256, 0, stream>>>(reps, rowsum);
    finalize_kernel<<<FINBLK, 256, 0, stream>>>(rowsum, pdot, partials,
                                                counter, out);
}

// Round 23
// 29.657 us; speedup vs baseline: 1.6215x; 1.0996x over previous
//
#include <hip/hip_runtime.h>
#include <hip/hip_fp8.h>
#include <stdint.h>

#define NPAIR 4096
#define N2    8192      // 2N rows
#define DIM   256
#define NTILE 8256      // 128*129/2 upper-triangle 64x64 tiles
#define FINBLK 16       // finalize blocks
// per-operand prescale: 16 * sqrt(log2(e)/T); E8M0 scale 2^-4 per side
// folds the 16*16=256 back out -> acc == log2(e)/T * sim exactly.
#define SCALE_IN 27.1782976f
#define SCALE_EXP 0x7B7B7B7B    // E8M0 2^-4 in every byte (opsel-proof)

typedef int   i32x4  __attribute__((ext_vector_type(4)));
typedef int   i32x8  __attribute__((ext_vector_type(8)));
typedef float f32x16 __attribute__((ext_vector_type(16)));

// e2m1 (OCP fp4) round-to-nearest code: levels 0,.5,1,1.5,2,3,4,6
static __device__ __forceinline__ uint32_t fp4_code(float v) {
    float av = fabsf(v);
    uint32_t c =
        av < 0.25f ? 0u :
        av < 0.75f ? 1u :
        av < 1.25f ? 2u :
        av < 1.75f ? 3u :
        av < 2.5f  ? 4u :
        av < 3.5f  ? 5u :
        av < 5.0f  ? 6u : 7u;     // >=5 -> 6.0 (saturate)
    return c | (v < 0.f ? 8u : 0u);
}

// reps FRAGMENT-TILED fp4 for mfma_scale 32x32x64 FMT=fp4:
// 1 KB tile = 32 rows x 64 k (4-bit). nibble index of (row i, dim d):
//   tile  = (i>>5)*4 + (d>>6)                    (1024 B each)
//   lane  = ((d>>5)&1)*32 + (i&31)               (16 B per lane)
//   nib   = d&31  -> byte nib>>1, nibble nib&1
// Fragment load: lane l reads ONE int4 at tile + l*16 (16 B = 32 fp4).
// Any within-K nibble-order mismatch vs HW cancels: A and B share the
// exact same layout, so a k-relabeling leaves sum_k a_k b_k invariant.

// ---------------- Kernel A: normalize + fp4 pack + pdot + zero bufs -------
__global__ __launch_bounds__(256) void normalize_kernel(
    const float* __restrict__ emb_i, const float* __restrict__ emb_j,
    uint8_t* __restrict__ reps, float* __restrict__ pdot,
    float* __restrict__ rowsum, float* __restrict__ partials,
    unsigned int* __restrict__ counter) {
    int i = blockIdx.x * 4 + (threadIdx.x >> 6);
    int l = threadIdx.x & 63;       // 4 floats each: dims 4l..4l+3
    float4 a = ((const float4*)(emb_i + (size_t)i * DIM))[l];
    float4 b = ((const float4*)(emb_j + (size_t)i * DIM))[l];
    float si = a.x*a.x + a.y*a.y + a.z*a.z + a.w*a.w;
    float sj = b.x*b.x + b.y*b.y + b.z*b.z + b.w*b.w;
    float dp = a.x*b.x + a.y*b.y + a.z*b.z + a.w*b.w;
    #pragma unroll
    for (int off = 32; off; off >>= 1) {
        si += __shfl_xor(si, off);
        sj += __shfl_xor(sj, off);
        dp += __shfl_xor(dp, off);
    }
    float ri = 1.0f / fmaxf(sqrtf(si), 1e-12f);
    float rj = 1.0f / fmaxf(sqrtf(sj), 1e-12f);
    float riS = ri * SCALE_IN, rjS = rj * SCALE_IN;

    uint32_t ua = fp4_code(a.x * riS)        | (fp4_code(a.y * riS) << 4)
                | (fp4_code(a.z * riS) << 8) | (fp4_code(a.w * riS) << 12);
    uint32_t ub = fp4_code(b.x * rjS)        | (fp4_code(b.y * rjS) << 4)
                | (fp4_code(b.z * rjS) << 8) | (fp4_code(b.w * rjS) << 12);

    // d0 = 4l: tile col = l>>4, khalf = (l>>3)&1, byte-in-lane = 2*(l&7)
    int ii = i + NPAIR;
    int kh  = (l >> 3) & 1;
    int bo  = 2 * (l & 7);
    int idxA = (((i  >> 5) * 4 + (l >> 4)) * 1024)
             + (kh * 32 + (i  & 31)) * 16 + bo;
    int idxB = (((ii >> 5) * 4 + (l >> 4)) * 1024)
             + (kh * 32 + (ii & 31)) * 16 + bo;
    *(uint16_t*)(reps + idxA) = (uint16_t)ua;
    *(uint16_t*)(reps + idxB) = (uint16_t)ub;

    if (l == 0) pdot[i] = dp * ri * rj;       // positives fp32, unscaled
    if (l < 2)  rowsum[2 * i + l] = 0.f;
    if (i == 0 && l == 0) {
        partials[0] = 0.f; partials[1] = 0.f; *counter = 0u;
    }
}

// ---------- Kernel B: BARRIER-FREE per-wave 64x64 tiles, MX-fp4 -----------
// r20/r22 structure; GEMM core on mfma_scale_f32_32x32x64_f8f6f4 with
// FMT=fp4 (cbsz=blgp=4): 2x MFMA rate and HALF the fragment bytes
// (1 int4 load per fragment). E8M0 scales 2^-4/side undo the 16x input
// prescale -> acc == log2(e)/T * sim; epilogue unchanged (bare exp2f,
// 32x32 C/D layout, butterfly multi-reduce, 2 disjoint atomics/lane).
__global__ __launch_bounds__(256, 4) void simexp_kernel(
    const uint8_t* __restrict__ reps, float* __restrict__ rowsum) {
    int t = threadIdx.x;
    int l = t & 63;

    // anti-diagonal decode over n=128 tile grid: C(d) = d*(257-d)/2
    int idx = blockIdx.x * 4 + (t >> 6);
    int d = (int)((257.0f - sqrtf(257.0f * 257.0f - 8.0f * (float)idx)) * 0.5f);
    while (d * (257 - d) / 2 > idx) --d;
    while ((d + 1) * (256 - d) / 2 <= idx) ++d;
    int i0 = idx - d * (257 - d) / 2;
    int brow = i0 * 64;
    int bcol = (i0 + d) * 64;
    int R0A = i0 * 2;               // 32-row fragment blocks (+mi)
    int R0B = (i0 + d) * 2;         // +ni

    f32x16 acc[2][2];
    #pragma unroll
    for (int mi = 0; mi < 2; ++mi)
        #pragma unroll
        for (int ni = 0; ni < 2; ++ni)
            acc[mi][ni] = (f32x16)(0.f);

    for (int ks = 0; ks < 4; ++ks) {    // 4 K-steps of 64
        i32x8 a[2], b[2];
        #pragma unroll
        for (int q = 0; q < 2; ++q) {
            const uint8_t* ta = reps + (size_t)(((R0A + q) * 4 + ks) * 1024);
            const uint8_t* tb = reps + (size_t)(((R0B + q) * 4 + ks) * 1024);
            i32x4 a0 = ((const i32x4*)ta)[l];
            i32x4 b0 = ((const i32x4*)tb)[l];
            a[q] = (i32x8){a0.x, a0.y, a0.z, a0.w, 0, 0, 0, 0};
            b[q] = (i32x8){b0.x, b0.y, b0.z, b0.w, 0, 0, 0, 0};
        }
        __builtin_amdgcn_s_setprio(1);
        #pragma unroll
        for (int mi = 0; mi < 2; ++mi)
            #pragma unroll
            for (int ni = 0; ni < 2; ++ni)
                acc[mi][ni] = __builtin_amdgcn_mfma_scale_f32_32x32x64_f8f6f4(
                    a[mi], b[ni], acc[mi][ni],
                    4, 4,               // cbsz=fp4, blgp=fp4
                    0, SCALE_EXP,       // opsel_a, scale_a = 2^-4
                    0, SCALE_EXP);      // opsel_b, scale_b = 2^-4
        __builtin_amdgcn_s_setprio(0);
    }

    // Epilogue. 32x32 C/D: col = lane&31, row = (v&3)+8*(v>>2)+4*(lane>>5)
    int c32 = l & 31;
    int h   = l >> 5;
    float csum[2] = {0.f, 0.f};

    if (d != 0) {                   // off-diagonal: unmasked, rows + cols
        float rpar[32];             // u = mi*16 + (v&3)+4*(v>>2)
        #pragma unroll
        for (int mi = 0; mi < 2; ++mi) {
            #pragma unroll
            for (int v = 0; v < 16; ++v) {
                float e0 = exp2f(acc[mi][0][v]);
                float e1 = exp2f(acc[mi][1][v]);
                csum[0] += e0;
                csum[1] += e1;
                rpar[mi * 16 + (v & 3) + 4 * (v >> 2)] = e0 + e1;
            }
        }
        // butterfly multi-reduce (31 shuffles): lane c32 ends with row sum u=c32
        bool s0 = (c32 & 1);
        float w16[16];
        #pragma unroll
        for (int i = 0; i < 16; ++i) {
            float keep = s0 ? rpar[2 * i + 1] : rpar[2 * i];
            float send = s0 ? rpar[2 * i]     : rpar[2 * i + 1];
            w16[i] = keep + __shfl_xor(send, 1);
        }
        bool s1 = (c32 & 2);
        float w8[8];
        #pragma unroll
        for (int i = 0; i < 8; ++i) {
            float keep = s1 ? w16[2 * i + 1] : w16[2 * i];
            float send = s1 ? w16[2 * i]     : w16[2 * i + 1];
            w8[i] = keep + __shfl_xor(send, 2);
        }
        bool s2 = (c32 & 4);
        float w4[4];
        #pragma unroll
        for (int i = 0; i < 4; ++i) {
            float keep = s2 ? w8[2 * i + 1] : w8[2 * i];
            float send = s2 ? w8[2 * i]     : w8[2 * i + 1];
            w4[i] = keep + __shfl_xor(send, 4);
        }
        bool s3 = (c32 & 8);
        float w2[2];
        #pragma unroll
        for (int i = 0; i < 2; ++i) {
            float keep = s3 ? w4[2 * i + 1] : w4[2 * i];
            float send = s3 ? w4[2 * i]     : w4[2 * i + 1];
            w2[i] = keep + __shfl_xor(send, 8);
        }
        bool s4 = (c32 & 16);
        float keep = s4 ? w2[1] : w2[0];
        float send = s4 ? w2[0] : w2[1];
        float rv = keep + __shfl_xor(send, 16);

        csum[0] += __shfl_xor(csum[0], 32);
        csum[1] += __shfl_xor(csum[1], 32);
        float cv = h ? csum[1] : csum[0];
        atomicAdd(&rowsum[bcol + h * 32 + c32], cv);     // 64 disjoint cols
        int grow = brow + (c32 >> 4) * 32 + (c32 & 3)
                 + 8 * ((c32 & 15) >> 2) + 4 * h;
        atomicAdd(&rowsum[grow], rv);                    // 64 disjoint rows
    } else {                        // diagonal tile: masked, cols only
        #pragma unroll
        for (int mi = 0; mi < 2; ++mi) {
            #pragma unroll
            for (int v = 0; v < 16; ++v) {
                int grow = brow + mi * 32 + (v & 3) + 8 * (v >> 2) + 4 * h;
                #pragma unroll
                for (int ni = 0; ni < 2; ++ni) {
                    float e = exp2f(acc[mi][ni][v]);
                    int gcol = bcol + ni * 32 + c32;
                    e = (grow == gcol) ? 0.f : e;        // main diagonal
                    csum[ni] += e;
                }
            }
        }
        csum[0] += __shfl_xor(csum[0], 32);
        csum[1] += __shfl_xor(csum[1], 32);
        float cv = h ? csum[1] : csum[0];
        atomicAdd(&rowsum[bcol + h * 32 + c32], cv);
    }
}

// ---------------- Kernel C: PARALLEL finalize (16 blocks) -----------------
__global__ __launch_bounds__(256) void finalize_kernel(
    const float* __restrict__ rowsum, const float* __restrict__ pdot,
    float* __restrict__ partials, unsigned int* __restrict__ counter,
    float* __restrict__ out) {
    int t = threadIdx.x;
    int g = blockIdx.x * 256 + t;       // 0..4095
    __shared__ float reds[4], redp[4];
    __shared__ int lastFlag;
    const float4* rs4 = (const float4*)rowsum;
    const float4* pd4 = (const float4*)pdot;
    float s = 0.f, p = 0.f;
    if (g < N2 / 4) {
        float4 v = rs4[g];
        s = __logf(v.x) + __logf(v.y) + __logf(v.z) + __logf(v.w);
    }
    if (g < NPAIR / 4) {
        float4 v = pd4[g];
        p = v.x + v.y + v.z + v.w;
    }
    #pragma unroll
    for (int off = 32; off; off >>= 1) {
        s += __shfl_xor(s, off);
        p += __shfl_xor(p, off);
    }
    if ((t & 63) == 0) { reds[t >> 6] = s; redp[t >> 6] = p; }
    __syncthreads();
    if (t == 0) {
        float S = reds[0] + reds[1] + reds[2] + reds[3];
        float P = redp[0] + redp[1] + redp[2] + redp[3];
        atomicAdd(&partials[0], S);
        atomicAdd(&partials[1], P);
        __threadfence();
        unsigned prev = atomicAdd(counter, 1u);
        lastFlag = (prev == FINBLK - 1);
        __threadfence();
    }
    __syncthreads();
    if (lastFlag && t == 0) {
        float S = __hip_atomic_load(&partials[0], __ATOMIC_ACQUIRE,
                                    __HIP_MEMORY_SCOPE_AGENT);
        float P = __hip_atomic_load(&partials[1], __ATOMIC_ACQUIRE,
                                    __HIP_MEMORY_SCOPE_AGENT);
        // loss = (sum log D - (2/T)*2*sum(dp)) / 2N ; (2/T)*2 folded: 4*P
        out[0] = (S - 4.0f * P) / (float)N2;
    }
}

extern "C" void kernel_launch(void* const* d_in, const int* in_sizes, int n_in,
                              void* d_out, int out_size, void* d_ws, size_t ws_size,
                              hipStream_t stream) {
    const float* emb_i = (const float*)d_in[0];
    const float* emb_j = (const float*)d_in[1];
    float* out = (float*)d_out;

    char* ws = (char*)d_ws;
    float*        rowsum   = (float*)ws;                    // 8192 * 4 B
    float*        pdot     = (float*)(ws + 32768);          // 4096 * 4 B
    float*        partials = (float*)(ws + 49152);          // 2 * 4 B
    unsigned int* counter  = (unsigned int*)(ws + 49216);   // 4 B
    uint8_t*      reps     = (uint8_t*)(ws + 65536);        // 1 MB fp4 tiled

    normalize_kernel<<<NPAIR / 4, 256, 0, stream>>>(emb_i, emb_j, reps, pdot,
                                                    rowsum, partials, counter);
    simexp_kernel<<<NTILE / 4, 256, 0, stream>>>(reps, rowsum);
    finalize_kernel<<<FINBLK, 256, 0, stream>>>(rowsum, pdot, partials,
                                                counter, out);
}